// Round 1
// baseline (309.835 us; speedup 1.0000x reference)
//
#include <hip/hip_runtime.h>
#include <hip/hip_bf16.h>
#include <stdint.h>

// Problem constants: B=128, S=512, I=128, Hd=512, G=3*Hd=1536, M=B*S=65536.
// Inputs/outputs FP32. Convert x/w_emb/w_ih to bf16 once (one fused kernel),
// bf16 MFMA GEMMs with fp32 accumulate, fp32 output.
//
// LDS bank-conflict note: tile rows are 64 bf16 = 128 B = 32 banks, so
// unswizzled fragment reads are 16-way conflicted. global_load_lds pins LDS
// slot = base+lane*16, so we swizzle the GLOBAL source: LDS slot (row, s)
// holds global chunk s^(row&7).
#define M_TOT   65536
#define I_DIM   128
#define HD      512
#define HOFF    33488896   // 128*511*512, element offset of h_last in d_out
#define HROW    261632     // 511*512, per-b row stride of H

typedef __bf16 bf16x8 __attribute__((ext_vector_type(8)));
typedef float f32x4 __attribute__((ext_vector_type(4)));

struct __align__(8) bf16x4_t { __hip_bfloat16 v[4]; };

// async global->LDS, 16B per lane (lane-scatter base+lane*16, m104/m108).
__device__ __forceinline__ void async_load16(const void* g, void* l) {
  __builtin_amdgcn_global_load_lds(
      (const __attribute__((address_space(1))) void*)g,
      (__attribute__((address_space(3))) void*)l, 16, 0, 0);
}

// v_rcp_f32: rel err 2^-22 — far below the 1.4e-2 abs threshold.
__device__ __forceinline__ float fastrcp(float x) {
  return __builtin_amdgcn_rcpf(x);
}
__device__ __forceinline__ float sigf(float x) {
  return fastrcp(1.0f + __expf(-x));
}
__device__ __forceinline__ float tanhfast(float x) {
  return 1.0f - 2.0f * fastrcp(__expf(2.0f * x) + 1.0f);
}

// ---------------------------------------------------------------------------
// Fused fp32 -> bf16 conversion for x, w_emb, w_ih (one launch).
// ---------------------------------------------------------------------------
#define N4_X   2097152                 // 65536*128/4
#define N4_WE  (N4_X + 16384)          // + 512*128/4
#define N4_WI  (N4_WE + 196608)        // + 1536*512/4
__global__ void cvt_all(const float* __restrict__ x,
                        const float* __restrict__ we,
                        const float* __restrict__ wi,
                        __hip_bfloat16* __restrict__ xb,
                        __hip_bfloat16* __restrict__ web,
                        __hip_bfloat16* __restrict__ wib) {
  const int i = blockIdx.x * blockDim.x + threadIdx.x;
  const float4* src;
  bf16x4_t* dst;
  int off;
  if (i < N4_X)       { src = (const float4*)x;  dst = (bf16x4_t*)xb;  off = i; }
  else if (i < N4_WE) { src = (const float4*)we; dst = (bf16x4_t*)web; off = i - N4_X; }
  else if (i < N4_WI) { src = (const float4*)wi; dst = (bf16x4_t*)wib; off = i - N4_WE; }
  else return;
  const float4 v = src[off];
  bf16x4_t o;
  o.v[0] = __float2bfloat16(v.x);
  o.v[1] = __float2bfloat16(v.y);
  o.v[2] = __float2bfloat16(v.z);
  o.v[3] = __float2bfloat16(v.w);
  dst[off] = o;
}

// ---------------------------------------------------------------------------
// Kernel 1: emb[m,h] = sum_i x[m,i]*w_emb[h,i] + b_emb[h]   (bf16 out -> ws)
// M=65536, N=512, K=128. Tile 128x128, BK=64, 2 K-iters. 4 waves, 64x64 each.
// Swizzled staging (see top). Epilogue repacks through LDS, bf16x8 stores.
// (unchanged this round — isolating the gru_gemm schedule change)
// ---------------------------------------------------------------------------
__global__ __launch_bounds__(256, 2) void emb_gemm(
    const __hip_bfloat16* __restrict__ x,      // (65536,128) bf16 (ws)
    const __hip_bfloat16* __restrict__ w_emb,  // (512,128)  N x K, bf16 (ws)
    const float* __restrict__ b_emb,           // (512) fp32
    __hip_bfloat16* __restrict__ emb)          // (65536,512) bf16 (ws)
{
  __shared__ __align__(16) __hip_bfloat16 smem[2 * 128 * 64];  // As ++ Bs, 32KB
  __hip_bfloat16* As = smem;
  __hip_bfloat16* Bs = smem + 128 * 64;

  const int tid  = threadIdx.x;
  const int w    = tid >> 6;
  const int lane = tid & 63;
  const int m0 = blockIdx.x * 128;
  const int n0 = blockIdx.y * 128;
  const int wm = (w >> 1) * 64;
  const int wn = (w & 1) * 64;
  const int lrow = lane >> 3;              // 0..7 (row within 8-row chunk)
  const int gc   = ((lane & 7) ^ lrow) * 8;  // swizzled global element offset
  const int l15 = lane & 15;
  const int q   = lane >> 4;
  const int sx  = l15 & 7;                 // row&7 for fragment rows

  f32x4 acc[4][4];
#pragma unroll
  for (int i = 0; i < 4; ++i)
#pragma unroll
    for (int j = 0; j < 4; ++j) acc[i][j] = (f32x4)0.0f;

#pragma unroll
  for (int kk = 0; kk < 2; ++kk) {
    const int k0 = kk * 64;
#pragma unroll
    for (int c = 0; c < 4; ++c) {
      const int chunk = w * 4 + c;
      const int row = chunk * 8 + lrow;
      async_load16(x + (size_t)(m0 + row) * I_DIM + k0 + gc,
                   (void*)&As[chunk * 8 * 64]);
      async_load16(w_emb + (size_t)(n0 + row) * I_DIM + k0 + gc,
                   (void*)&Bs[chunk * 8 * 64]);
    }
    __syncthreads();
#pragma unroll
    for (int ks = 0; ks < 2; ++ks) {
      const int s = ((ks * 4 + q) ^ sx) * 8;   // swizzled LDS chunk
      bf16x8 af[4], bfr[4];
#pragma unroll
      for (int mi = 0; mi < 4; ++mi)
        af[mi] = *(const bf16x8*)&As[(wm + mi * 16 + l15) * 64 + s];
#pragma unroll
      for (int ni = 0; ni < 4; ++ni)
        bfr[ni] = *(const bf16x8*)&Bs[(wn + ni * 16 + l15) * 64 + s];
#pragma unroll
      for (int ni = 0; ni < 4; ++ni)
#pragma unroll
        for (int mi = 0; mi < 4; ++mi)
          acc[mi][ni] = __builtin_amdgcn_mfma_f32_16x16x32_bf16(
              af[mi], bfr[ni], acc[mi][ni], 0, 0, 0);
    }
    __syncthreads();   // all LDS reads done -> safe to reuse smem in epilogue
  }

  // Epilogue: +b_emb, repack wave-private 64x64 tile through LDS, 16B stores.
  // C/D layout: col=lane&15, row=q*4+reg (m89).
  __hip_bfloat16* ebuf = &smem[w * 64 * 64];   // 8KB per wave, wave-private
#pragma unroll
  for (int ni = 0; ni < 4; ++ni) {
    const float bias = b_emb[n0 + wn + ni * 16 + l15];
#pragma unroll
    for (int mi = 0; mi < 4; ++mi)
#pragma unroll
      for (int r = 0; r < 4; ++r)
        ebuf[(mi * 16 + q * 4 + r) * 64 + ni * 16 + l15] =
            __float2bfloat16(acc[mi][ni][r] + bias);
  }
  // wave-private buffer: compiler-inserted lgkmcnt orders write->read
#pragma unroll
  for (int i = 0; i < 8; ++i) {
    const int row  = i * 8 + (lane >> 3);
    const int colb = (lane & 7) * 8;
    const bf16x8 v = *(const bf16x8*)&ebuf[row * 64 + colb];
    *(bf16x8*)&emb[(size_t)(m0 + wm + row) * HD + n0 + wn + colb] = v;
  }
}

// ---------------------------------------------------------------------------
// Kernel 2: gi[m, g*512+h] = sum_h' emb[m,h']*w_ih[g*512+h, h'] ; gate math.
//
// NEW (this round): 3-phase counted-vmcnt pipeline (T3+T4+T5 per guide §5.5).
// BM=256 rows x 64 h-cols x 3 gates per block; BK=64, 8 K-tiles; 8 waves
// (4M x 2N), wave tile 64M x 32N per gate -> acc[3][4][2]. LDS double-buffered
// (2 x (A 32KB ++ B 24KB) = 112KB, 1 block/CU).
//
// Pipeline (per K-tile T, phases = one gate each, 16 MFMA per phase):
//   ph0: ds_read A(8)+B0(4) | issue B2(T+1)->nxt    | bar; lgkm0; MFMA g0; vmcnt(W0); bar
//   ph1: ds_read B1(4)      | issue A,B0(T+2)->cur  | bar; lgkm0; MFMA g1; vmcnt(W1); bar
//   ph2: ds_read B2(4)      | issue B1(T+2)->cur    | bar; lgkm0; MFMA g2; vmcnt(W2); bar
// Overwrite safety: each region's last reader is >=1 full barrier pair before
// its re-staging (A/B0 read ph0 -> written ph1; B1 read ph1 -> written ph2;
// B2 read ph2 -> written next-tile ph0, into the *other* buffer).
// vmcnt waits (steady state, each wave issues exactly 7 loads/tile, FIFO):
//   W0=8 (B1(T) ready), W1=12 (B2(T) ready), W2=8 (A,B0(T+1) ready).
// Loads get 3-5 phases of latency budget; vmcnt never drains to 0 mid-loop.
// ---------------------------------------------------------------------------

__device__ __forceinline__ void stage_A(const __hip_bfloat16* __restrict__ emb,
                                        int m0, int k, __hip_bfloat16* As,
                                        int w, int lrow, int gc) {
#pragma unroll
  for (int c = 0; c < 4; ++c) {
    const int chunk = w * 4 + c;
    async_load16(emb + (size_t)(m0 + chunk * 8 + lrow) * HD + k + gc,
                 (void*)&As[chunk * 512]);
  }
}
__device__ __forceinline__ void stage_Bg(const __hip_bfloat16* __restrict__ w_ih,
                                         int h0, int g, int k, __hip_bfloat16* Bs,
                                         int w, int lrow, int gc) {
  async_load16(w_ih + (size_t)(g * HD + h0 + w * 8 + lrow) * HD + k + gc,
               (void*)&Bs[g * 4096 + w * 512]);
}

__device__ __forceinline__ void read_Bfrag(const __hip_bfloat16* Bs, int g,
                                           int wn, int l15, int q, int sx,
                                           bf16x8 out[2][2]) {
#pragma unroll
  for (int ks = 0; ks < 2; ++ks) {
    const int s = ((ks * 4 + q) ^ sx) * 8;
#pragma unroll
    for (int ni = 0; ni < 2; ++ni)
      out[ks][ni] = *(const bf16x8*)&Bs[g * 4096 + (wn + ni * 16 + l15) * 64 + s];
  }
}

__device__ __forceinline__ void mfma_gate(const bf16x8 af[2][4],
                                          const bf16x8 bg[2][2],
                                          f32x4 (*accg)[2]) {
#pragma unroll
  for (int ks = 0; ks < 2; ++ks)
#pragma unroll
    for (int ni = 0; ni < 2; ++ni)
#pragma unroll
      for (int mi = 0; mi < 4; ++mi)
        accg[mi][ni] = __builtin_amdgcn_mfma_f32_16x16x32_bf16(
            af[ks][mi], bg[ks][ni], accg[mi][ni], 0, 0, 0);
}

// One K-tile. ISSUE bit0: B2(T+1)->An/Bn; bit1: A,B0(T+2)->Aw/Bw; bit2: B1(T+2)->Bw.
template <int W0, int W1, int W2, int ISSUE>
__device__ __forceinline__ void gru_tile(
    const __hip_bfloat16* __restrict__ emb, const __hip_bfloat16* __restrict__ w_ih,
    __hip_bfloat16* Ac, __hip_bfloat16* Bc,       // current buffers (read; T+2 write)
    __hip_bfloat16* An, __hip_bfloat16* Bn,       // next buffers (T+1 write)
    int m0, int h0, int k0,
    int w, int wm, int wn, int lrow, int gc, int l15, int q, int sx,
    f32x4 (&acc)[3][4][2])
{
  bf16x8 af[2][4];
  // ---------------- phase 0: gate 0 ----------------
  {
    bf16x8 b0[2][2];
#pragma unroll
    for (int ks = 0; ks < 2; ++ks) {
      const int s = ((ks * 4 + q) ^ sx) * 8;
#pragma unroll
      for (int mi = 0; mi < 4; ++mi)
        af[ks][mi] = *(const bf16x8*)&Ac[(wm + mi * 16 + l15) * 64 + s];
    }
    read_Bfrag(Bc, 0, wn, l15, q, sx, b0);
    if (ISSUE & 1) stage_Bg(w_ih, h0, 2, k0 + 64, Bn, w, lrow, gc);
    __builtin_amdgcn_s_barrier();
    asm volatile("s_waitcnt lgkmcnt(0)" ::: "memory");
    __builtin_amdgcn_sched_barrier(0);
    __builtin_amdgcn_s_setprio(1);
    mfma_gate(af, b0, acc[0]);
    __builtin_amdgcn_s_setprio(0);
    asm volatile("s_waitcnt vmcnt(%0)" :: "i"(W0) : "memory");
    __builtin_amdgcn_s_barrier();
  }
  // ---------------- phase 1: gate 1 ----------------
  {
    bf16x8 b1[2][2];
    read_Bfrag(Bc, 1, wn, l15, q, sx, b1);
    if (ISSUE & 2) {
      stage_A(emb, m0, k0 + 128, Ac, w, lrow, gc);
      stage_Bg(w_ih, h0, 0, k0 + 128, Bc, w, lrow, gc);
    }
    __builtin_amdgcn_s_barrier();
    asm volatile("s_waitcnt lgkmcnt(0)" ::: "memory");
    __builtin_amdgcn_sched_barrier(0);
    __builtin_amdgcn_s_setprio(1);
    mfma_gate(af, b1, acc[1]);
    __builtin_amdgcn_s_setprio(0);
    asm volatile("s_waitcnt vmcnt(%0)" :: "i"(W1) : "memory");
    __builtin_amdgcn_s_barrier();
  }
  // ---------------- phase 2: gate 2 ----------------
  {
    bf16x8 b2[2][2];
    read_Bfrag(Bc, 2, wn, l15, q, sx, b2);
    if (ISSUE & 4) stage_Bg(w_ih, h0, 1, k0 + 128, Bc, w, lrow, gc);
    __builtin_amdgcn_s_barrier();
    asm volatile("s_waitcnt lgkmcnt(0)" ::: "memory");
    __builtin_amdgcn_sched_barrier(0);
    __builtin_amdgcn_s_setprio(1);
    mfma_gate(af, b2, acc[2]);
    __builtin_amdgcn_s_setprio(0);
    asm volatile("s_waitcnt vmcnt(%0)" :: "i"(W2) : "memory");
    __builtin_amdgcn_s_barrier();
  }
}

__global__ __launch_bounds__(512, 2) void gru_gemm(
    const __hip_bfloat16* __restrict__ emb,   // (65536,512) bf16 (ws)
    const __hip_bfloat16* __restrict__ w_ih,  // (1536,512) N x K, bf16 (ws)
    const float* __restrict__ b_ih,           // (1536) fp32
    const float* __restrict__ b_hh,           // (1536) fp32
    float* __restrict__ out)                  // H(128,511,512) ++ h_last(128,512) fp32
{
  __shared__ __align__(16) char smem[114688];            // 2 x (A 32K ++ B 24K)
  __hip_bfloat16* sA0 = (__hip_bfloat16*)smem;
  __hip_bfloat16* sB0 = (__hip_bfloat16*)(smem + 32768);
  __hip_bfloat16* sA1 = (__hip_bfloat16*)(smem + 57344);
  __hip_bfloat16* sB1 = (__hip_bfloat16*)(smem + 57344 + 32768);

  const int tid  = threadIdx.x;
  const int w    = tid >> 6;                 // 0..7
  const int lane = tid & 63;
  const int m0 = blockIdx.x * 256;
  const int h0 = blockIdx.y * 64;
  const int wm = (w >> 1) * 64;              // 0,64,128,192
  const int wn = (w & 1) * 32;
  const int lrow = lane >> 3;
  const int gc   = ((lane & 7) ^ lrow) * 8;  // swizzled global element offset
  const int l15 = lane & 15;
  const int q   = lane >> 4;
  const int sx  = l15 & 7;

  f32x4 acc[3][4][2];
#pragma unroll
  for (int g = 0; g < 3; ++g)
#pragma unroll
    for (int i = 0; i < 4; ++i)
#pragma unroll
      for (int j = 0; j < 2; ++j) acc[g][i][j] = (f32x4)0.0f;

  // Prologue: issue in the exact FIFO order the steady-state waits assume:
  // [A(0)x4, B0(0)] [B1(0)] [B2(0)] [A(1)x4, B0(1)] [B1(1)]  = 12 loads.
  stage_A(emb, m0, 0, sA0, w, lrow, gc);
  stage_Bg(w_ih, h0, 0, 0, sB0, w, lrow, gc);
  stage_Bg(w_ih, h0, 1, 0, sB0, w, lrow, gc);
  stage_Bg(w_ih, h0, 2, 0, sB0, w, lrow, gc);
  stage_A(emb, m0, 64, sA1, w, lrow, gc);
  stage_Bg(w_ih, h0, 0, 64, sB1, w, lrow, gc);
  stage_Bg(w_ih, h0, 1, 64, sB1, w, lrow, gc);
  asm volatile("s_waitcnt vmcnt(7)" ::: "memory");   // A(0),B0(0) (oldest 5) done
  __builtin_amdgcn_s_barrier();

  // Steady tiles 0..5 (full issue), then exact-count tail tiles 6,7.
#pragma unroll 2
  for (int t = 0; t < 6; ++t) {
    __hip_bfloat16* Ac = (t & 1) ? sA1 : sA0;
    __hip_bfloat16* Bc = (t & 1) ? sB1 : sB0;
    __hip_bfloat16* An = (t & 1) ? sA0 : sA1;
    __hip_bfloat16* Bn = (t & 1) ? sB0 : sB1;
    gru_tile<8, 12, 8, 7>(emb, w_ih, Ac, Bc, An, Bn, m0, h0, t * 64,
                          w, wm, wn, lrow, gc, l15, q, sx, acc);
  }
  gru_tile<8, 7, 2, 1>(emb, w_ih, sA0, sB0, sA1, sB1, m0, h0, 384,
                       w, wm, wn, lrow, gc, l15, q, sx, acc);   // t=6
  gru_tile<1, 0, 0, 0>(emb, w_ih, sA1, sB1, sA0, sB0, m0, h0, 448,
                       w, wm, wn, lrow, gc, l15, q, sx, acc);   // t=7
  __syncthreads();   // all LDS reads done -> safe to reuse smem in epilogue

  // Epilogue: gate math (v_rcp), repack wave tile (64M x 32h fp32) through
  // LDS with stride 40 floats (40%32=8 -> 2-way on float4 reads = free),
  // float4 stores. 64*40*4 = 10240 B per wave, 8 waves = 81920 <= 114688.
  float* obuf = (float*)(smem + w * 10240);
#pragma unroll
  for (int ni = 0; ni < 2; ++ni) {
    const int col = h0 + wn + ni * 16 + l15;
    const float br = b_ih[col] + b_hh[col];
    const float bz = b_ih[HD + col] + b_hh[HD + col];
    const float bn = b_ih[2 * HD + col];
    const float bhn = b_hh[2 * HD + col];
#pragma unroll
    for (int mi = 0; mi < 4; ++mi) {
#pragma unroll
      for (int r = 0; r < 4; ++r) {
        const float rr = sigf(acc[0][mi][ni][r] + br);
        const float zz = sigf(acc[1][mi][ni][r] + bz);
        const float nn = tanhfast(acc[2][mi][ni][r] + bn + rr * bhn);
        obuf[(mi * 16 + q * 4 + r) * 40 + ni * 16 + l15] = (1.0f - zz) * nn;
      }
    }
  }
  // wave-private region: compiler-inserted lgkmcnt orders write->read
  const int srow = lane >> 3;        // 0..7
  const int scol = (lane & 7) * 4;   // 0,4,...,28
#pragma unroll
  for (int i = 0; i < 8; ++i) {
    const int row = i * 8 + srow;    // m_local 0..63
    const float4 v = *(const float4*)&obuf[row * 40 + scol];
    const int m = m0 + wm + row;
    const int b = m >> 9;            // m / 512
    const int s = m & 511;           // m % 512
    float* dst = (s < 511)
        ? out + (size_t)b * HROW + (size_t)s * HD + h0 + wn + scol
        : out + (size_t)HOFF + (size_t)b * HD + h0 + wn + scol;
    *(float4*)dst = v;
  }
}

extern "C" void kernel_launch(void* const* d_in, const int* in_sizes, int n_in,
                              void* d_out, int out_size, void* d_ws, size_t ws_size,
                              hipStream_t stream) {
  const float* x_f     = (const float*)d_in[0];   // (128,512,128)
  const float* w_emb_f = (const float*)d_in[1];   // (512,128)
  const float* b_emb   = (const float*)d_in[2];   // (512)
  const float* w_ih_f  = (const float*)d_in[3];   // (1536,512)
  const float* b_ih    = (const float*)d_in[4];   // (1536)
  const float* b_hh    = (const float*)d_in[5];   // (1536)
  float* out = (float*)d_out;

  // ws layout (bytes):
  //   [0, 64Mi)            emb bf16 (65536*512*2)
  //   [64Mi, +16Mi)        x bf16   (65536*128*2)
  //   [80Mi, +128Ki)       w_emb bf16
  //   [80Mi+128Ki, +1.5Mi) w_ih bf16
  char* ws = (char*)d_ws;
  __hip_bfloat16* emb_bf   = (__hip_bfloat16*)(ws);
  __hip_bfloat16* x_bf     = (__hip_bfloat16*)(ws + 67108864);
  __hip_bfloat16* w_emb_bf = (__hip_bfloat16*)(ws + 67108864 + 16777216);
  __hip_bfloat16* w_ih_bf  = (__hip_bfloat16*)(ws + 67108864 + 16777216 + 131072);

  cvt_all<<<(N4_WI + 255) / 256, 256, 0, stream>>>(
      x_f, w_emb_f, w_ih_f, x_bf, w_emb_bf, w_ih_bf);

  emb_gemm<<<dim3(M_TOT / 128, HD / 128), 256, 0, stream>>>(
      x_bf, w_emb_bf, b_emb, emb_bf);
  gru_gemm<<<dim3(M_TOT / 256, HD / 64), 512, 0, stream>>>(
      emb_bf, w_ih_bf, b_ih, b_hh, out);
}

// Round 2
// 292.467 us; speedup vs baseline: 1.0594x; 1.0594x over previous
//
#include <hip/hip_runtime.h>
#include <hip/hip_bf16.h>
#include <stdint.h>

// Problem constants: B=128, S=512, I=128, Hd=512, G=3*Hd=1536, M=B*S=65536.
// Inputs/outputs FP32. Convert x/w_emb/w_ih to bf16 once (one fused kernel),
// bf16 MFMA GEMMs with fp32 accumulate, fp32 output.
//
// LDS bank-conflict note: tile rows are 64 bf16 = 128 B = 32 banks, so
// unswizzled fragment reads are 16-way conflicted. global_load_lds pins LDS
// slot = base+lane*16, so we swizzle the GLOBAL source: LDS slot (row, s)
// holds global chunk s^(row&7).
//
// Round-2 schedule (both GEMMs): double-buffered LDS, ONE barrier per K-tile.
//   tile t: [issue full STAGE(t+1) -> other buffer] [ds_read frags(t)]
//           [MFMA clusters, setprio] [__syncthreads = vmcnt0+lgkm0+s_barrier]
// Staging latency (~500+ cyc of MFMA+ds_read cover per wave) overlaps compute;
// 2 blocks/CU (LDS exactly 2x40KB / 2x32KB) keeps inter-block overlap (m114).
#define M_TOT   65536
#define I_DIM   128
#define HD      512
#define HOFF    33488896   // 128*511*512, element offset of h_last in d_out
#define HROW    261632     // 511*512, per-b row stride of H

typedef __bf16 bf16x8 __attribute__((ext_vector_type(8)));
typedef float f32x4 __attribute__((ext_vector_type(4)));

struct __align__(8) bf16x4_t { __hip_bfloat16 v[4]; };

// async global->LDS, 16B per lane (lane-scatter base+lane*16, m104/m108).
__device__ __forceinline__ void async_load16(const void* g, void* l) {
  __builtin_amdgcn_global_load_lds(
      (const __attribute__((address_space(1))) void*)g,
      (__attribute__((address_space(3))) void*)l, 16, 0, 0);
}

// v_rcp_f32: rel err 2^-22 — far below the 1.4e-2 abs threshold.
__device__ __forceinline__ float fastrcp(float x) {
  return __builtin_amdgcn_rcpf(x);
}
__device__ __forceinline__ float sigf(float x) {
  return fastrcp(1.0f + __expf(-x));
}
__device__ __forceinline__ float tanhfast(float x) {
  return 1.0f - 2.0f * fastrcp(__expf(2.0f * x) + 1.0f);
}

// ---------------------------------------------------------------------------
// Fused fp32 -> bf16 conversion for x, w_emb, w_ih (one launch).
// ---------------------------------------------------------------------------
#define N4_X   2097152                 // 65536*128/4
#define N4_WE  (N4_X + 16384)          // + 512*128/4
#define N4_WI  (N4_WE + 196608)        // + 1536*512/4
__global__ void cvt_all(const float* __restrict__ x,
                        const float* __restrict__ we,
                        const float* __restrict__ wi,
                        __hip_bfloat16* __restrict__ xb,
                        __hip_bfloat16* __restrict__ web,
                        __hip_bfloat16* __restrict__ wib) {
  const int i = blockIdx.x * blockDim.x + threadIdx.x;
  const float4* src;
  bf16x4_t* dst;
  int off;
  if (i < N4_X)       { src = (const float4*)x;  dst = (bf16x4_t*)xb;  off = i; }
  else if (i < N4_WE) { src = (const float4*)we; dst = (bf16x4_t*)web; off = i - N4_X; }
  else if (i < N4_WI) { src = (const float4*)wi; dst = (bf16x4_t*)wib; off = i - N4_WE; }
  else return;
  const float4 v = src[off];
  bf16x4_t o;
  o.v[0] = __float2bfloat16(v.x);
  o.v[1] = __float2bfloat16(v.y);
  o.v[2] = __float2bfloat16(v.z);
  o.v[3] = __float2bfloat16(v.w);
  dst[off] = o;
}

// ---------------------------------------------------------------------------
// Kernel 1: emb[m,h] = sum_i x[m,i]*w_emb[h,i] + b_emb[h]   (bf16 out -> ws)
// M=65536, N=512, K=128. Tile 128x128, BK=64, 2 K-tiles. 4 waves, 64x64 each.
// Double-buffered (2 x 32KB), one barrier per tile, prefetch at tile top.
// ---------------------------------------------------------------------------
__device__ __forceinline__ void emb_stage(const __hip_bfloat16* __restrict__ x,
                                          const __hip_bfloat16* __restrict__ w_emb,
                                          int m0, int n0, int k,
                                          __hip_bfloat16* As, __hip_bfloat16* Bs,
                                          int w, int lrow, int gc) {
#pragma unroll
  for (int c = 0; c < 4; ++c) {
    const int chunk = w * 4 + c;
    const int row = chunk * 8 + lrow;
    async_load16(x + (size_t)(m0 + row) * I_DIM + k + gc, (void*)&As[chunk * 512]);
    async_load16(w_emb + (size_t)(n0 + row) * I_DIM + k + gc, (void*)&Bs[chunk * 512]);
  }
}

__global__ __launch_bounds__(256, 2) void emb_gemm(
    const __hip_bfloat16* __restrict__ x,      // (65536,128) bf16 (ws)
    const __hip_bfloat16* __restrict__ w_emb,  // (512,128)  N x K, bf16 (ws)
    const float* __restrict__ b_emb,           // (512) fp32
    __hip_bfloat16* __restrict__ emb)          // (65536,512) bf16 (ws)
{
  // 2 buffers x (As 8192 el ++ Bs 8192 el) = 65536 B -> 2 blocks/CU
  __shared__ __align__(16) __hip_bfloat16 smem[32768];

  const int tid  = threadIdx.x;
  const int w    = tid >> 6;
  const int lane = tid & 63;
  const int m0 = blockIdx.x * 128;
  const int n0 = blockIdx.y * 128;
  const int wm = (w >> 1) * 64;
  const int wn = (w & 1) * 64;
  const int lrow = lane >> 3;              // 0..7 (row within 8-row chunk)
  const int gc   = ((lane & 7) ^ lrow) * 8;  // swizzled global element offset
  const int l15 = lane & 15;
  const int q   = lane >> 4;
  const int sx  = l15 & 7;                 // row&7 for fragment rows

  f32x4 acc[4][4];
#pragma unroll
  for (int i = 0; i < 4; ++i)
#pragma unroll
    for (int j = 0; j < 4; ++j) acc[i][j] = (f32x4)0.0f;

  // prologue: stage tile 0 -> buf0; __syncthreads drains vmcnt.
  emb_stage(x, w_emb, m0, n0, 0, smem, smem + 8192, w, lrow, gc);
  __syncthreads();

#pragma unroll
  for (int t = 0; t < 2; ++t) {
    const __hip_bfloat16* As = smem + (t & 1) * 16384;
    const __hip_bfloat16* Bs = As + 8192;
    if (t == 0)  // prefetch tile 1 -> buf1 while computing tile 0
      emb_stage(x, w_emb, m0, n0, 64, smem + 16384, smem + 16384 + 8192,
                w, lrow, gc);
    __builtin_amdgcn_sched_barrier(0);     // pin stage issue at tile top
#pragma unroll
    for (int ks = 0; ks < 2; ++ks) {
      const int s = ((ks * 4 + q) ^ sx) * 8;   // swizzled LDS chunk
      bf16x8 af[4], bfr[4];
#pragma unroll
      for (int mi = 0; mi < 4; ++mi)
        af[mi] = *(const bf16x8*)&As[(wm + mi * 16 + l15) * 64 + s];
#pragma unroll
      for (int ni = 0; ni < 4; ++ni)
        bfr[ni] = *(const bf16x8*)&Bs[(wn + ni * 16 + l15) * 64 + s];
      __builtin_amdgcn_s_setprio(1);
#pragma unroll
      for (int ni = 0; ni < 4; ++ni)
#pragma unroll
        for (int mi = 0; mi < 4; ++mi)
          acc[mi][ni] = __builtin_amdgcn_mfma_f32_16x16x32_bf16(
              af[mi], bfr[ni], acc[mi][ni], 0, 0, 0);
      __builtin_amdgcn_s_setprio(0);
    }
    if (t == 0) __syncthreads();   // vmcnt(0)+lgkmcnt(0)+barrier: buf1 ready
  }

  // Epilogue: +b_emb, repack wave-private 64x64 tile through LDS, 16B stores.
  // ebuf lives in buf0 [0,16384 el); last tile read buf1 -> disjoint, no
  // barrier needed (all waves passed t0's barrier; t1 touches only buf1).
  // C/D layout: col=lane&15, row=q*4+reg (m89).
  __hip_bfloat16* ebuf = &smem[w * 64 * 64];   // 8KB per wave, wave-private
#pragma unroll
  for (int ni = 0; ni < 4; ++ni) {
    const float bias = b_emb[n0 + wn + ni * 16 + l15];
#pragma unroll
    for (int mi = 0; mi < 4; ++mi)
#pragma unroll
      for (int r = 0; r < 4; ++r)
        ebuf[(mi * 16 + q * 4 + r) * 64 + ni * 16 + l15] =
            __float2bfloat16(acc[mi][ni][r] + bias);
  }
  // wave-private buffer: compiler-inserted lgkmcnt orders write->read
#pragma unroll
  for (int i = 0; i < 8; ++i) {
    const int row  = i * 8 + (lane >> 3);
    const int colb = (lane & 7) * 8;
    const bf16x8 v = *(const bf16x8*)&ebuf[row * 64 + colb];
    *(bf16x8*)&emb[(size_t)(m0 + wm + row) * HD + n0 + wn + colb] = v;
  }
}

// ---------------------------------------------------------------------------
// Kernel 2: gi[m, g*512+h] = sum_h' emb[m,h']*w_ih[g*512+h, h'] ; gate math.
// Per block: 128 M-rows x 64 h-cols x 3 gates. BK=64, 8 K-tiles.
// 4 waves (2x2): each wave 64(M) x 32(h) per gate -> acc[3][4][2].
// Round-2: double-buffered (2 x 40KB), one barrier per K-tile, full next-tile
// prefetch at tile top, setprio around MFMA clusters. 2 blocks/CU.
// ---------------------------------------------------------------------------
__device__ __forceinline__ void gru_stage(const __hip_bfloat16* __restrict__ emb,
                                          const __hip_bfloat16* __restrict__ w_ih,
                                          int m0, int h0, int k,
                                          __hip_bfloat16* As, __hip_bfloat16* Bs,
                                          int w, int lrow, int gc) {
  // A tile: 128 rows -> 16 chunks, 4 per wave
#pragma unroll
  for (int c = 0; c < 4; ++c) {
    const int chunk = w * 4 + c;
    async_load16(emb + (size_t)(m0 + chunk * 8 + lrow) * HD + k + gc,
                 (void*)&As[chunk * 512]);
  }
  // B tiles: per gate 64 rows -> 8 chunks, 2 per wave
#pragma unroll
  for (int g = 0; g < 3; ++g)
#pragma unroll
    for (int c = 0; c < 2; ++c) {
      const int chunk = w * 2 + c;
      async_load16(w_ih + (size_t)(g * HD + h0 + chunk * 8 + lrow) * HD + k + gc,
                   (void*)&Bs[g * 4096 + chunk * 512]);
    }
}

__device__ __forceinline__ void read_Bfrag(const __hip_bfloat16* Bs, int g,
                                           int wn, int l15, int q, int sx,
                                           bf16x8 out[2][2]) {
#pragma unroll
  for (int ks = 0; ks < 2; ++ks) {
    const int s = ((ks * 4 + q) ^ sx) * 8;
#pragma unroll
    for (int ni = 0; ni < 2; ++ni)
      out[ks][ni] = *(const bf16x8*)&Bs[g * 4096 + (wn + ni * 16 + l15) * 64 + s];
  }
}

__device__ __forceinline__ void mfma_gate(const bf16x8 af[2][4],
                                          const bf16x8 bg[2][2],
                                          f32x4 (*accg)[2]) {
#pragma unroll
  for (int ks = 0; ks < 2; ++ks)
#pragma unroll
    for (int ni = 0; ni < 2; ++ni)
#pragma unroll
      for (int mi = 0; mi < 4; ++mi)
        accg[mi][ni] = __builtin_amdgcn_mfma_f32_16x16x32_bf16(
            af[ks][mi], bg[ks][ni], accg[mi][ni], 0, 0, 0);
}

__global__ __launch_bounds__(256, 2) void gru_gemm(
    const __hip_bfloat16* __restrict__ emb,   // (65536,512) bf16 (ws)
    const __hip_bfloat16* __restrict__ w_ih,  // (1536,512) N x K, bf16 (ws)
    const float* __restrict__ b_ih,           // (1536) fp32
    const float* __restrict__ b_hh,           // (1536) fp32
    float* __restrict__ out)                  // H(128,511,512) ++ h_last(128,512) fp32
{
  // 2 buffers x (As 16K ++ Bs 24K) = 81920 B -> exactly 2 blocks/CU (160KB).
  __shared__ __align__(16) char smem[81920];

  const int tid  = threadIdx.x;
  const int w    = tid >> 6;
  const int lane = tid & 63;
  const int m0 = blockIdx.x * 128;
  const int h0 = blockIdx.y * 64;
  const int wm = (w >> 1) * 64;
  const int wn = (w & 1) * 32;
  const int lrow = lane >> 3;
  const int gc   = ((lane & 7) ^ lrow) * 8;  // swizzled global element offset
  const int l15 = lane & 15;
  const int q   = lane >> 4;
  const int sx  = l15 & 7;

  f32x4 acc[3][4][2];
#pragma unroll
  for (int g = 0; g < 3; ++g)
#pragma unroll
    for (int i = 0; i < 4; ++i)
#pragma unroll
      for (int j = 0; j < 2; ++j) acc[g][i][j] = (f32x4)0.0f;

  // prologue: stage tile 0 -> buf0; __syncthreads drains vmcnt.
  gru_stage(emb, w_ih, m0, h0, 0,
            (__hip_bfloat16*)smem, (__hip_bfloat16*)(smem + 16384),
            w, lrow, gc);
  __syncthreads();

#pragma unroll
  for (int t = 0; t < 8; ++t) {
    const __hip_bfloat16* As = (const __hip_bfloat16*)(smem + (t & 1) * 40960);
    const __hip_bfloat16* Bs = (const __hip_bfloat16*)(smem + (t & 1) * 40960 + 16384);
    if (t < 7) {  // full prefetch of tile t+1 into the other buffer
      __hip_bfloat16* An = (__hip_bfloat16*)(smem + ((t + 1) & 1) * 40960);
      __hip_bfloat16* Bn = (__hip_bfloat16*)(smem + ((t + 1) & 1) * 40960 + 16384);
      gru_stage(emb, w_ih, m0, h0, (t + 1) * 64, An, Bn, w, lrow, gc);
    }
    __builtin_amdgcn_sched_barrier(0);     // pin stage issue at tile top
    bf16x8 af[2][4];
#pragma unroll
    for (int ks = 0; ks < 2; ++ks) {
      const int s = ((ks * 4 + q) ^ sx) * 8;   // swizzled LDS chunk
#pragma unroll
      for (int mi = 0; mi < 4; ++mi)
        af[ks][mi] = *(const bf16x8*)&As[(wm + mi * 16 + l15) * 64 + s];
    }
#pragma unroll
    for (int g = 0; g < 3; ++g) {
      bf16x8 b[2][2];
      read_Bfrag(Bs, g, wn, l15, q, sx, b);
      __builtin_amdgcn_s_setprio(1);
      mfma_gate(af, b, acc[g]);
      __builtin_amdgcn_s_setprio(0);
    }
    // One barrier per tile: drains this wave's stages (vmcnt0) + LDS reads
    // (lgkm0), then syncs -> other buffer ready, this buffer re-writable.
    if (t < 7) __syncthreads();
  }

  // Epilogue: gate math (v_rcp), repack wave tile (64M x 32h fp32) through
  // LDS with stride 40 floats (40%32=8 -> 2-way on float4 reads = free),
  // float4 stores. obuf lives in buf0 [0,40960); last tile (t=7) read buf1
  // [40960,81920) -> disjoint, and all waves passed t6's barrier, so no
  // barrier needed before reuse. 64*40*4 = 10240 B per wave, 4 waves = 40960.
  float* obuf = (float*)(smem + w * 10240);
#pragma unroll
  for (int ni = 0; ni < 2; ++ni) {
    const int col = h0 + wn + ni * 16 + l15;
    const float br = b_ih[col] + b_hh[col];
    const float bz = b_ih[HD + col] + b_hh[HD + col];
    const float bn = b_ih[2 * HD + col];
    const float bhn = b_hh[2 * HD + col];
#pragma unroll
    for (int mi = 0; mi < 4; ++mi) {
#pragma unroll
      for (int r = 0; r < 4; ++r) {
        const float rr = sigf(acc[0][mi][ni][r] + br);
        const float zz = sigf(acc[1][mi][ni][r] + bz);
        const float nn = tanhfast(acc[2][mi][ni][r] + bn + rr * bhn);
        obuf[(mi * 16 + q * 4 + r) * 40 + ni * 16 + l15] = (1.0f - zz) * nn;
      }
    }
  }
  // wave-private region: compiler-inserted lgkmcnt orders write->read
  const int srow = lane >> 3;        // 0..7
  const int scol = (lane & 7) * 4;   // 0,4,...,28
#pragma unroll
  for (int i = 0; i < 8; ++i) {
    const int row = i * 8 + srow;    // m_local 0..63
    const float4 v = *(const float4*)&obuf[row * 40 + scol];
    const int m = m0 + wm + row;
    const int b = m >> 9;            // m / 512
    const int s = m & 511;           // m % 512
    float* dst = (s < 511)
        ? out + (size_t)b * HROW + (size_t)s * HD + h0 + wn + scol
        : out + (size_t)HOFF + (size_t)b * HD + h0 + wn + scol;
    *(float4*)dst = v;
  }
}

extern "C" void kernel_launch(void* const* d_in, const int* in_sizes, int n_in,
                              void* d_out, int out_size, void* d_ws, size_t ws_size,
                              hipStream_t stream) {
  const float* x_f     = (const float*)d_in[0];   // (128,512,128)
  const float* w_emb_f = (const float*)d_in[1];   // (512,128)
  const float* b_emb   = (const float*)d_in[2];   // (512)
  const float* w_ih_f  = (const float*)d_in[3];   // (1536,512)
  const float* b_ih    = (const float*)d_in[4];   // (1536)
  const float* b_hh    = (const float*)d_in[5];   // (1536)
  float* out = (float*)d_out;

  // ws layout (bytes):
  //   [0, 64Mi)            emb bf16 (65536*512*2)
  //   [64Mi, +16Mi)        x bf16   (65536*128*2)
  //   [80Mi, +128Ki)       w_emb bf16
  //   [80Mi+128Ki, +1.5Mi) w_ih bf16
  char* ws = (char*)d_ws;
  __hip_bfloat16* emb_bf   = (__hip_bfloat16*)(ws);
  __hip_bfloat16* x_bf     = (__hip_bfloat16*)(ws + 67108864);
  __hip_bfloat16* w_emb_bf = (__hip_bfloat16*)(ws + 67108864 + 16777216);
  __hip_bfloat16* w_ih_bf  = (__hip_bfloat16*)(ws + 67108864 + 16777216 + 131072);

  cvt_all<<<(N4_WI + 255) / 256, 256, 0, stream>>>(
      x_f, w_emb_f, w_ih_f, x_bf, w_emb_bf, w_ih_bf);

  emb_gemm<<<dim3(M_TOT / 128, HD / 128), 256, 0, stream>>>(
      x_bf, w_emb_bf, b_emb, emb_bf);
  gru_gemm<<<dim3(M_TOT / 128, HD / 64), 256, 0, stream>>>(
      emb_bf, w_ih_bf, b_ih, b_hh, out);
}